// Round 1
// 427.538 us; speedup vs baseline: 1.0594x; 1.0594x over previous
//
#include <hip/hip_runtime.h>
#include <cstdint>
#include <cstddef>

typedef unsigned short ushort_t;
typedef __bf16 bf16x8 __attribute__((ext_vector_type(8)));
typedef float f32x4 __attribute__((ext_vector_type(4)));
typedef float f32x4v __attribute__((ext_vector_type(4)));
typedef unsigned short u16x4 __attribute__((ext_vector_type(4)));
typedef unsigned short u16x8 __attribute__((ext_vector_type(8)));

__device__ __forceinline__ ushort_t f2bf(float x) {
    union { float f; uint32_t u; } v; v.f = x;
    return (ushort_t)((v.u + 0x7FFFu + ((v.u >> 16) & 1u)) >> 16);
}

// async global->LDS, 16B per lane. LDS dest = wave-uniform base + lane*16.
__device__ __forceinline__ void gld_lds16(const void* g, void* l) {
    __builtin_amdgcn_global_load_lds(
        (const __attribute__((address_space(1))) uint32_t*)g,
        (__attribute__((address_space(3))) uint32_t*)l,
        16, 0, 0);
}

// ---------------------------------------------------------------------------
// Kernel 1: W [H,V] fp32 -> Wt [V,H] bf16 (B^T layout for the GEMM).
// ---------------------------------------------------------------------------
__global__ __launch_bounds__(256) void transpose_convert(
    const float* __restrict__ Wm, ushort_t* __restrict__ Wt, int H, int V)
{
    __shared__ ushort_t tile[64][72];
    const int v0 = blockIdx.x * 64;
    const int k0 = blockIdx.y * 64;
    const int tid = threadIdx.x;

    #pragma unroll
    for (int p = 0; p < 4; ++p) {
        const int krow = p * 16 + (tid >> 4);
        const int vcol = (tid & 15) * 4;
        const f32x4v w = *(const f32x4v*)&Wm[(size_t)(k0 + krow) * V + v0 + vcol];
        tile[vcol + 0][krow] = f2bf(w.x);
        tile[vcol + 1][krow] = f2bf(w.y);
        tile[vcol + 2][krow] = f2bf(w.z);
        tile[vcol + 3][krow] = f2bf(w.w);
    }
    __syncthreads();
    #pragma unroll
    for (int p = 0; p < 2; ++p) {
        const int idx = p * 256 + tid;
        const int v = idx >> 3;
        const int c = (idx & 7) * 8;
        const u16x8 val = *(const u16x8*)&tile[v][c];
        *(u16x8*)&Wt[(size_t)(v0 + v) * H + k0 + c] = val;
    }
}

// ---------------------------------------------------------------------------
// Kernel 2: segment mean, one WAVE per (b,w).
// ---------------------------------------------------------------------------
__global__ __launch_bounds__(256) void seg_mean(
    const float* __restrict__ enc,
    const int*   __restrict__ seg,
    ushort_t*    __restrict__ merged,
    int S, int H, int W)
{
    const int wave = threadIdx.x >> 6;
    const int lane = threadIdx.x & 63;
    const int bw = blockIdx.x * 4 + wave;
    const int b  = bw >> 8;
    const int w  = bw & 255;
    const int* srow = seg + (size_t)b * S;

    int l = 0, r = S;
    while (l < r) { int m = (l + r) >> 1; if (srow[m] < w) l = m + 1; else r = m; }
    const int lo = l;
    r = S;
    while (l < r) { int m = (l + r) >> 1; if (srow[m] < w + 1) l = m + 1; else r = m; }
    const int hi = l;

    const int cnt = hi - lo;
    const float scale = (cnt > 0) ? (1.0f / (float)cnt) : 0.0f;
    const float* erow = enc + (size_t)b * S * H;
    ushort_t* orow = merged + (size_t)bw * H;

    #pragma unroll
    for (int c = 0; c < 3; ++c) {
        const int col = c * 256 + lane * 4;
        f32x4v s = {0.f, 0.f, 0.f, 0.f};
        for (int t = lo; t < hi; ++t) {
            const f32x4v v = *(const f32x4v*)&erow[(size_t)t * H + col];
            s.x += v.x; s.y += v.y; s.z += v.z; s.w += v.w;
        }
        u16x4 o;
        o.x = f2bf(s.x * scale); o.y = f2bf(s.y * scale);
        o.z = f2bf(s.z * scale); o.w = f2bf(s.w * scale);
        *(u16x4*)&orow[col] = o;
    }
}

// ---------------------------------------------------------------------------
// Kernel 3: C[M,N] = A[M,K] * Bt[N,K]^T + bias[N]   (bf16 in, fp32 out)
// 256x256 tile, BK=64, 8 waves (2M x 4N), 4-phase-per-K-tile schedule:
//   phase: {ds_read frags || stage 1 half-tile (2x global_load_lds)} ->
//          barrier -> setprio(1) -> 16 MFMA -> setprio(0) -> barrier
// Counted s_waitcnt vmcnt(4) once per K-tile (never 0 in main loop).
// LDS slots: As[parity][half] 128rows x 64cols each; XOR row-swizzle
// ((row&7)<<4 on the 16B chunk) applied on BOTH the global source address
// (pre-swizzle, since global_load_lds writes linearly) and the ds_read addr.
// Staging-half definitions chosen so every slot is overwritten >=1 full
// phase after its last read:
//   A-half s = tile rows with bit6==s (rows interleave at 64 granularity)
//   B-half s = tile rows with bit5==s (rows interleave at 32 granularity)
// Read phases per tile: p1 reads A-h0+B-h0, p2 B-h1, p3 A-h1, p4 none.
// Stage stream: p1: A-h1(t+1), p2: B-h1(t+1), p3: A-h0(t+2), p4: B-h0(t+2).
// ---------------------------------------------------------------------------

#define BAR() do { asm volatile("" ::: "memory"); \
                   __builtin_amdgcn_s_barrier(); \
                   asm volatile("" ::: "memory"); } while (0)

#define STG_A(U, S) do { \
    const ushort_t* g_ = Ag + (U) * 64 + (size_t)(S) * 64 * K; \
    char* l_ = ldsA + ((((U) & 1) * 2 + (S)) * 16384); \
    gld_lds16(g_, l_); \
    gld_lds16(g_ + (size_t)128 * K, l_ + 8192); \
} while (0)

#define STG_B(U, S) do { \
    const ushort_t* g_ = Bg + (U) * 64 + (size_t)(S) * 32 * K; \
    char* l_ = ldsB + ((((U) & 1) * 2 + (S)) * 16384); \
    gld_lds16(g_, l_); \
    gld_lds16(g_ + (size_t)128 * K, l_ + 8192); \
} while (0)

#define LDA(DST, MS, I, KK) \
    DST = *(const bf16x8*)(Ar + cur * 32768 + (MS) * 16384 + \
          (wm * 64 + (I) * 16 + r15) * 128 + (((KK) * 64 + quad * 16) ^ rswz))

#define LDB(DST, NS, J, KK) \
    DST = *(const bf16x8*)(Br + cur * 32768 + (NS) * 16384 + \
          (wn * 32 + (J) * 16 + r15) * 128 + (((KK) * 64 + quad * 16) ^ rswz))

#define MFMA_PH(MS, NS, BF) do { \
    __builtin_amdgcn_s_setprio(1); \
    _Pragma("unroll") \
    for (int i_ = 0; i_ < 4; ++i_) { \
      _Pragma("unroll") \
      for (int j_ = 0; j_ < 2; ++j_) { \
        acc[MS][i_][NS][j_] = __builtin_amdgcn_mfma_f32_16x16x32_bf16( \
            af[i_][0], BF[j_][0], acc[MS][i_][NS][j_], 0, 0, 0); \
        acc[MS][i_][NS][j_] = __builtin_amdgcn_mfma_f32_16x16x32_bf16( \
            af[i_][1], BF[j_][1], acc[MS][i_][NS][j_], 0, 0, 0); \
      } \
    } \
    __builtin_amdgcn_s_setprio(0); \
} while (0)

__global__ __launch_bounds__(512, 2) void gemm_bt256(
    const ushort_t* __restrict__ A,   // [M,K] bf16 (merged)
    const ushort_t* __restrict__ Bt,  // [N,K] bf16 (Wt)
    const float*    __restrict__ bias,// [N]
    float*          __restrict__ C,   // [M,N]
    int M, int N, int K)
{
    __shared__ ushort_t As[2][2][8192];   // [parity][half] 128x64 bf16, 64 KB
    __shared__ ushort_t Bs[2][2][8192];   // 64 KB

    const int tid  = threadIdx.x;
    const int wave = tid >> 6;
    const int lane = tid & 63;
    const int r15  = lane & 15;
    const int quad = lane >> 4;
    const int wm   = wave >> 2;          // 0..1
    const int wn   = wave & 3;           // 0..3
    const int rswz = (r15 & 7) << 4;     // read-side swizzle (bytes)

    // T1: bijective XCD swizzle (nwg=1024, 1024%8==0)
    const int wg  = blockIdx.x;
    const int swz = (wg & 7) * 128 + (wg >> 3);
    const int m0  = (swz >> 5) * 256;
    const int n0  = (swz & 31) * 256;

    // staging geometry: thread covers LDS linear bytes (r*512+tid)*16, r=0,1
    const int rho0 = tid >> 3;                           // 0..63
    const int cBb  = (tid & 7) * 16;                     // byte col in 128B row
    const int colA = (cBb ^ ((rho0 & 7) << 4)) >> 1;     // pre-swizzled src col (elems)
    const int grB0 = ((rho0 >> 5) << 6) + (rho0 & 31);   // B row for half s=0, round 0

    const ushort_t* Ag = A  + (size_t)(m0 + rho0) * K + colA;
    const ushort_t* Bg = Bt + (size_t)(n0 + grB0) * K + colA;
    char* ldsA = (char*)As + wave * 1024;
    char* ldsB = (char*)Bs + wave * 1024;
    const char* Ar = (const char*)As;
    const char* Br = (const char*)Bs;

    const int T = K >> 6;   // 12 K-tiles

    f32x4 acc[2][4][2][2] = {};   // [msub][i][nsub][j]

    // prologue: tile0 fully + tile1 sh0 halves, then wait tile0 landed
    STG_A(0, 0); STG_B(0, 0); STG_A(0, 1); STG_B(0, 1);
    STG_A(1, 0); STG_B(1, 0);
    asm volatile("s_waitcnt vmcnt(4)" ::: "memory");
    BAR();

    bf16x8 af[4][2], bf0[2][2], bf1[2][2];

    for (int t = 0; t < T; ++t) {
        const int cur = t & 1;
        int u1 = t + 1; if (u1 >= T) u1 = t - 1;   // parity-preserving clamp
        int u2 = t + 2; if (u2 >= T) u2 = t;       // identical-byte rewrite at tail

        // ---- phase 1: quadrant (ms=0, ns=0) ----
        #pragma unroll
        for (int i = 0; i < 4; ++i) { LDA(af[i][0], 0, i, 0); LDA(af[i][1], 0, i, 1); }
        #pragma unroll
        for (int j = 0; j < 2; ++j) { LDB(bf0[j][0], 0, j, 0); LDB(bf0[j][1], 0, j, 1); }
        STG_A(u1, 1);
        BAR();
        MFMA_PH(0, 0, bf0);
        BAR();

        // ---- phase 2: quadrant (ms=0, ns=1) ----
        #pragma unroll
        for (int j = 0; j < 2; ++j) { LDB(bf1[j][0], 1, j, 0); LDB(bf1[j][1], 1, j, 1); }
        STG_B(u1, 1);
        BAR();
        MFMA_PH(0, 1, bf1);
        BAR();

        // ---- phase 3: quadrant (ms=1, ns=0) ----
        #pragma unroll
        for (int i = 0; i < 4; ++i) { LDA(af[i][0], 1, i, 0); LDA(af[i][1], 1, i, 1); }
        STG_A(u2, 0);
        BAR();
        MFMA_PH(1, 0, bf0);
        BAR();

        // ---- phase 4: quadrant (ms=1, ns=1), counted vmcnt once per K-tile ----
        STG_B(u2, 0);
        BAR();
        MFMA_PH(1, 1, bf1);
        asm volatile("s_waitcnt vmcnt(4)" ::: "memory");
        BAR();
    }

    // epilogue: C/D layout col = lane&15, row = quad*4 + reg
    #pragma unroll
    for (int ms = 0; ms < 2; ++ms) {
        #pragma unroll
        for (int i = 0; i < 4; ++i) {
            const int row = m0 + wm * 128 + ms * 64 + i * 16 + quad * 4;
            #pragma unroll
            for (int ns = 0; ns < 2; ++ns) {
                #pragma unroll
                for (int j = 0; j < 2; ++j) {
                    const int col = n0 + wn * 64 + ns * 32 + j * 16 + r15;
                    const float bv = bias[col];
                    float* cp = C + (size_t)row * N + col;
                    #pragma unroll
                    for (int r = 0; r < 4; ++r)
                        cp[(size_t)r * N] = acc[ms][i][ns][j][r] + bv;
                }
            }
        }
    }
}

// ---------------------------------------------------------------------------
extern "C" void kernel_launch(void* const* d_in, const int* in_sizes, int n_in,
                              void* d_out, int out_size, void* d_ws, size_t ws_size,
                              hipStream_t stream) {
    const float* enc  = (const float*)d_in[0];  // [B,S,H] fp32
    const int*   seg  = (const int*)d_in[1];    // [B,S]
    const float* Wm   = (const float*)d_in[2];  // [H,V] fp32
    const float* bias = (const float*)d_in[3];  // [V]

    const int B = 32, S = 512, H = 768, V = 8192, WMAX = 256;
    const int M = B * WMAX;  // 8192

    ushort_t* Wt     = (ushort_t*)d_ws;               // [V,H] bf16 : 12.58 MB
    ushort_t* merged = Wt + (size_t)V * H;            // [M,H] bf16 : 12.58 MB
    float*    out    = (float*)d_out;                 // [M,V] fp32

    hipLaunchKernelGGL(transpose_convert, dim3(V / 64, H / 64), dim3(256), 0, stream,
                       Wm, Wt, H, V);
    hipLaunchKernelGGL(seg_mean, dim3(M / 4), dim3(256), 0, stream,
                       enc, seg, merged, S, H, WMAX);
    hipLaunchKernelGGL(gemm_bt256, dim3((M / 256) * (V / 256)), dim3(512), 0, stream,
                       merged, Wt, bias, out, M, V, H);
}